// Round 6
// baseline (418.448 us; speedup 1.0000x reference)
//
#include <hip/hip_runtime.h>
#include <math.h>

#define BB 64
#define NN 197
#define HH 10
#define DD 64
#define CC 640
#define C3 1920
#define LR 64
#define MTOT (BB*NN)          // 12608
#define SCALE 0.125f

typedef unsigned short u16;
typedef __bf16 bf16x8 __attribute__((ext_vector_type(8)));
typedef float f32x4 __attribute__((ext_vector_type(4)));

__device__ __forceinline__ void split_bf16(float f, u16& hi, u16& lo) {
  unsigned u = __float_as_uint(f);
  unsigned r = u + 0x7FFF + ((u >> 16) & 1);
  u16 hb = (u16)(r >> 16);
  float fh = __uint_as_float((unsigned)hb << 16);
  float dl = f - fh;
  unsigned u2 = __float_as_uint(dl);
  unsigned r2 = u2 + 0x7FFF + ((u2 >> 16) & 1);
  hi = hb; lo = (u16)(r2 >> 16);
}

__device__ __forceinline__ u16 bf16rn(float f) {
  unsigned u = __float_as_uint(f);
  return (u16)((u + 0x7FFF + ((u >> 16) & 1)) >> 16);
}
__device__ __forceinline__ float bf16tof(u16 v) {
  return __uint_as_float((unsigned)v << 16);
}

// ---------------------------------------------------------------------------
// K1: w_eff = perm3(w_qkv + (lora_a @ lora_b)^T) -> bf16 hi/lo split
// ---------------------------------------------------------------------------
__global__ __launch_bounds__(256) void k_weff(
    const float* __restrict__ w_qkv, const float* __restrict__ la,
    const float* __restrict__ lb, u16* __restrict__ whi, u16* __restrict__ wlo) {
  int idx = blockIdx.x * 256 + threadIdx.x;      // covers 1920*640
  int i = idx / CC, j = idx % CC;
  int src = 3 * (i % CC) + (i / CC);
  float acc = w_qkv[(size_t)src * CC + j];
  const float* laj = la + (size_t)j * LR;
  const float* lbs = lb + src;
  #pragma unroll 8
  for (int r = 0; r < LR; ++r) acc = fmaf(laj[r], lbs[(size_t)r * C3], acc);
  u16 h, l; split_bf16(acc, h, l);
  whi[idx] = h; wlo[idx] = l;
}

// fp32 -> bf16 hi/lo split
__global__ __launch_bounds__(256) void k_cvt(
    const float* __restrict__ in, u16* __restrict__ hi, u16* __restrict__ lo, int n4) {
  int i = blockIdx.x * 256 + threadIdx.x;
  if (i >= n4) return;
  float4 v = ((const float4*)in)[i];
  float f[4] = {v.x, v.y, v.z, v.w};
  ushort4 H, L;
  u16 hh, ll;
  split_bf16(f[0], hh, ll); H.x = hh; L.x = ll;
  split_bf16(f[1], hh, ll); H.y = hh; L.y = ll;
  split_bf16(f[2], hh, ll); H.z = hh; L.z = ll;
  split_bf16(f[3], hh, ll); H.w = hh; L.w = ll;
  ((ushort4*)hi)[i] = H;
  ((ushort4*)lo)[i] = L;
}

__device__ __forceinline__ int perm640(int i) {
  return (i < 214) ? 3 * i : (i < 427 ? 3 * (i - 214) + 1 : 3 * (i - 427) + 2);
}

__global__ __launch_bounds__(256) void k_cvtw(
    const float* __restrict__ wp, u16* __restrict__ hi, u16* __restrict__ lo) {
  int idx = blockIdx.x * 256 + threadIdx.x;      // covers 640*640
  int i = idx / CC, j = idx % CC;
  float v = wp[(size_t)perm640(i) * CC + j];
  u16 h, l; split_bf16(v, h, l);
  hi[idx] = h; lo[idx] = l;
}

// tabK: rows 0..29 tkv, 30..59 tkh, 60..63 zero -> bf16 hi/lo [64][64]
__global__ __launch_bounds__(256) void k_prep(
    const float* __restrict__ tkv, const float* __restrict__ tkh,
    u16* __restrict__ thi, u16* __restrict__ tlo) {
  for (int idx = threadIdx.x; idx < 4096; idx += 256) {
    int row = idx >> 6, d = idx & 63;
    float v = row < 30 ? tkv[row * 64 + d] : (row < 60 ? tkh[(row - 30) * 64 + d] : 0.f);
    u16 hh, ll; split_bf16(v, hh, ll);
    thi[idx] = hh; tlo[idx] = ll;
  }
}

// ---------------------------------------------------------------------------
// Split-bf16 MFMA GEMM, fused 3-pass (hh, lh, hl per k-step). 128x128, BK=64.
// ---------------------------------------------------------------------------
template<int OSPLIT>
__global__ __launch_bounds__(256) void k_gemm_mfma(
    const u16* __restrict__ Ahi, const u16* __restrict__ Alo,
    const u16* __restrict__ Bhi, const u16* __restrict__ Blo,
    const float* __restrict__ bias, float* __restrict__ Cc,
    u16* __restrict__ Chi, u16* __restrict__ Clo,
    int M, int Nc) {
  __shared__ u16 AsH[128][64];
  __shared__ u16 AsL[128][64];
  __shared__ u16 BsH[128][64];
  __shared__ u16 BsL[128][64];
  int t = threadIdx.x, w = t >> 6, l = t & 63;
  int m0 = blockIdx.x * 128, n0 = blockIdx.y * 128;
  int wr = w >> 1, wc = w & 1;
  f32x4 acc[4][4] = {};
  int srow = l >> 3;
  int scol = (l & 7) * 8;

  for (int k0 = 0; k0 < 640; k0 += 64) {
    #pragma unroll
    for (int j = 0; j < 4; ++j) {
      int row = 32 * w + 8 * j + srow;
      int ga = m0 + row; if (ga >= M) ga = M - 1;
      size_t offA = (size_t)ga * 640 + k0 + scol;
      size_t offB = (size_t)(n0 + row) * 640 + k0 + scol;
      __builtin_amdgcn_global_load_lds(
          (const __attribute__((address_space(1))) void*)(Ahi + offA),
          (__attribute__((address_space(3))) void*)(&AsH[32 * w + 8 * j][0]), 16, 0, 0);
      __builtin_amdgcn_global_load_lds(
          (const __attribute__((address_space(1))) void*)(Alo + offA),
          (__attribute__((address_space(3))) void*)(&AsL[32 * w + 8 * j][0]), 16, 0, 0);
      __builtin_amdgcn_global_load_lds(
          (const __attribute__((address_space(1))) void*)(Bhi + offB),
          (__attribute__((address_space(3))) void*)(&BsH[32 * w + 8 * j][0]), 16, 0, 0);
      __builtin_amdgcn_global_load_lds(
          (const __attribute__((address_space(1))) void*)(Blo + offB),
          (__attribute__((address_space(3))) void*)(&BsL[32 * w + 8 * j][0]), 16, 0, 0);
    }
    __syncthreads();
    int fr = l & 15, fq = l >> 4;
    #pragma unroll
    for (int ks = 0; ks < 2; ++ks) {
      bf16x8 ah[4], al[4], bh[4], bl[4];
      #pragma unroll
      for (int mi = 0; mi < 4; ++mi) {
        ah[mi] = *(const bf16x8*)&AsH[wr * 64 + 16 * mi + fr][ks * 32 + fq * 8];
        al[mi] = *(const bf16x8*)&AsL[wr * 64 + 16 * mi + fr][ks * 32 + fq * 8];
        bh[mi] = *(const bf16x8*)&BsH[wc * 64 + 16 * mi + fr][ks * 32 + fq * 8];
        bl[mi] = *(const bf16x8*)&BsL[wc * 64 + 16 * mi + fr][ks * 32 + fq * 8];
      }
      #pragma unroll
      for (int mi = 0; mi < 4; ++mi)
        #pragma unroll
        for (int ni = 0; ni < 4; ++ni) {
          acc[mi][ni] = __builtin_amdgcn_mfma_f32_16x16x32_bf16(ah[mi], bh[ni], acc[mi][ni], 0, 0, 0);
          acc[mi][ni] = __builtin_amdgcn_mfma_f32_16x16x32_bf16(al[mi], bh[ni], acc[mi][ni], 0, 0, 0);
          acc[mi][ni] = __builtin_amdgcn_mfma_f32_16x16x32_bf16(ah[mi], bl[ni], acc[mi][ni], 0, 0, 0);
        }
    }
    __syncthreads();
  }

  int fr = l & 15, fq = l >> 4;
  #pragma unroll
  for (int mi = 0; mi < 4; ++mi) {
    #pragma unroll
    for (int ni = 0; ni < 4; ++ni) {
      int col = n0 + wc * 64 + 16 * ni + fr;
      float bv = bias[col];
      #pragma unroll
      for (int r = 0; r < 4; ++r) {
        int row = m0 + wr * 64 + 16 * mi + fq * 4 + r;
        if (row < M) {
          float val = acc[mi][ni][r] + bv;
          if (OSPLIT) {
            u16 hh, ll; split_bf16(val, hh, ll);
            Chi[(size_t)row * Nc + col] = hh;
            Clo[(size_t)row * Nc + col] = ll;
          } else {
            Cc[(size_t)row * Nc + col] = val;
          }
        }
      }
    }
  }
}

// ---------------------------------------------------------------------------
// Fused MFMA attention v3: 512 thr (8 waves), q-tile 128, LDS 79,872 B
// -> 2 blocks/CU. QK^T stays 3-pass split (serial Khi->Klo staging); PV uses
// hi-only P and V (error ~1.5e-4). Rel-v buckets via VALU pass over P in LDS
// (no M matrix). Per-half epilogue. LDS overlays:
//   [0,34816)     K[272][64]u16 (hi then lo)  -> post-B4: Phi[64][224]u16
//   [34816,51200) PvPh[128][64]bf16 -> post-B5: BvBh[64][32]f32 + TvL[60][64]bf16
//   [51200,79872) Vhi[64][224]u16
// ---------------------------------------------------------------------------
__global__ __launch_bounds__(512, 4) void k_attn(
    const u16* __restrict__ qkvhi, const u16* __restrict__ qkvlo,
    const u16* __restrict__ tabKhi, const u16* __restrict__ tabKlo,
    const float* __restrict__ tvv, const float* __restrict__ tvh,
    u16* __restrict__ ohi, u16* __restrict__ olo) {
  __shared__ __align__(16) unsigned char LDS[79872];
  unsigned char* Ak  = LDS;                    // [272][64]u16
  unsigned char* Phi = LDS;                    // post-B4: [64][224]u16
  unsigned char* PvB = LDS + 34816;            // [128][64] bf16
  float* BvBh = (float*)(LDS + 34816);         // post-B5: [64][32] f32
  u16*   TvL  = (u16*)(LDS + 43008);           // [60][64] bf16
  unsigned char* Vh  = LDS + 51200;            // [64][224]u16

  int bh = blockIdx.x, b = bh / HH, h = bh % HH, qt = blockIdx.y;
  int t = threadIdx.x, w = t >> 6, l = t & 63;
  int fr = l & 15, fq = l >> 4;
  int q0 = 128 * qt;
  const size_t qbase = (size_t)(b * NN) * C3;

  // ---- K hi + tab hi glds (pre-swizzled source, linear dest) ----
  int kr = l >> 3;
  int chunk = ((l & 7) ^ (kr & 7)) * 8;
  for (int i = w; i < 26; i += 8) {
    int kk = 8 * i + kr; if (kk > 196) kk = 196;
    size_t src = qbase + (size_t)kk * C3 + CC + h * DD + chunk;
    __builtin_amdgcn_global_load_lds(
        (const __attribute__((address_space(1))) void*)(qkvhi + src),
        (__attribute__((address_space(3))) void*)(Ak + i * 1024), 16, 0, 0);
  }
  {
    int tr = 8 * w + kr;
    __builtin_amdgcn_global_load_lds(
        (const __attribute__((address_space(1))) void*)(tabKhi + tr * 64 + chunk),
        (__attribute__((address_space(3))) void*)(Ak + 26624 + w * 1024), 16, 0, 0);
  }
  // ---- V^T hi staging (scatter, conflict-free swizzle) ----
  for (int idx = t; idx < 1576; idx += 512) {
    int k = idx >> 3, d0v = (idx & 7) * 8;
    size_t off = qbase + (size_t)k * C3 + 2 * CC + h * DD + d0v;
    uint4 vh4 = *(const uint4*)(qkvhi + off);
    u16 eh[8] = {(u16)vh4.x, (u16)(vh4.x >> 16), (u16)vh4.y, (u16)(vh4.y >> 16),
                 (u16)vh4.z, (u16)(vh4.z >> 16), (u16)vh4.w, (u16)(vh4.w >> 16)};
    #pragma unroll
    for (int jj = 0; jj < 8; ++jj) {
      int d = d0v + jj;
      int byte = (d * 224 + k) * 2; byte ^= (((d & 7) ^ ((d >> 3) & 7)) << 4);
      *(u16*)(Vh + byte) = eh[jj];
    }
  }
  for (int idx = t; idx < 64 * 27; idx += 512) {   // zero-pad cols 197..223
    int d = idx / 27, k = 197 + idx % 27;
    int byte = (d * 224 + k) * 2; byte ^= (((d & 7) ^ ((d >> 3) & 7)) << 4);
    *(u16*)(Vh + byte) = 0;
  }

  // ---- Q fragments ----
  bool active = (q0 + 16 * w) < NN;
  bf16x8 qh[2], ql_[2];
  {
    int qg = q0 + 16 * w + fr; int qc = qg > 196 ? 196 : qg;
    const u16* qr  = qkvhi + qbase + (size_t)qc * C3 + h * DD;
    const u16* qr2 = qkvlo + qbase + (size_t)qc * C3 + h * DD;
    qh[0]  = *(const bf16x8*)(qr + 8 * fq);
    qh[1]  = *(const bf16x8*)(qr + 32 + 8 * fq);
    ql_[0] = *(const bf16x8*)(qr2 + 8 * fq);
    ql_[1] = *(const bf16x8*)(qr2 + 32 + 8 * fq);
  }
  __syncthreads();   // B1

  // ---- S passes 1+2 vs Khi ----
  f32x4 sacc[17] = {};
  if (active) {
    #pragma unroll
    for (int ks = 0; ks < 2; ++ks)
      #pragma unroll
      for (int nf = 0; nf < 17; ++nf) {
        int row = 16 * nf + fr;
        int byte = row * 128 + 64 * ks + 16 * fq; byte ^= (row & 7) << 4;
        bf16x8 kf = *(const bf16x8*)(Ak + byte);
        sacc[nf] = __builtin_amdgcn_mfma_f32_16x16x32_bf16(qh[ks],  kf, sacc[nf], 0, 0, 0);
        sacc[nf] = __builtin_amdgcn_mfma_f32_16x16x32_bf16(ql_[ks], kf, sacc[nf], 0, 0, 0);
      }
  }
  __syncthreads();   // B2

  // ---- K lo + tab lo staging (overlay) ----
  for (int i = w; i < 26; i += 8) {
    int kk = 8 * i + kr; if (kk > 196) kk = 196;
    size_t src = qbase + (size_t)kk * C3 + CC + h * DD + chunk;
    __builtin_amdgcn_global_load_lds(
        (const __attribute__((address_space(1))) void*)(qkvlo + src),
        (__attribute__((address_space(3))) void*)(Ak + i * 1024), 16, 0, 0);
  }
  {
    int tr = 8 * w + kr;
    __builtin_amdgcn_global_load_lds(
        (const __attribute__((address_space(1))) void*)(tabKlo + tr * 64 + chunk),
        (__attribute__((address_space(3))) void*)(Ak + 26624 + w * 1024), 16, 0, 0);
  }
  __syncthreads();   // B3

  // ---- S pass 3 (qh . Klo), PvPh write, softmax, pack ----
  unsigned pk01[13], pk23[13];
  if (active) {
    #pragma unroll
    for (int ks = 0; ks < 2; ++ks)
      #pragma unroll
      for (int nf = 0; nf < 17; ++nf) {
        int row = 16 * nf + fr;
        int byte = row * 128 + 64 * ks + 16 * fq; byte ^= (row & 7) << 4;
        bf16x8 kf = *(const bf16x8*)(Ak + byte);
        sacc[nf] = __builtin_amdgcn_mfma_f32_16x16x32_bf16(qh[ks], kf, sacc[nf], 0, 0, 0);
      }
    // Pv/Ph (frags 13..16) -> LDS bf16 (wave-local rows, swz by row)
    #pragma unroll
    for (int nf = 13; nf < 17; ++nf)
      #pragma unroll
      for (int r = 0; r < 4; ++r) {
        int c = 16 * (nf - 13) + fr;
        if (c < 60) {
          int row = 16 * w + 4 * fq + r;
          int byte = (row * 64 + c) * 2; byte ^= (row & 7) << 4;
          *(u16*)(PvB + byte) = bf16rn(sacc[nf][r]);
        }
      }
    float ex[13][4];
    float mrow[4] = {-1e30f, -1e30f, -1e30f, -1e30f};
    #pragma unroll
    for (int r = 0; r < 4; ++r) {
      int ql2 = 16 * w + 4 * fq + r; int qg = q0 + ql2;
      int qc = qg > 196 ? 196 : qg;
      int gq = (qc > 0) ? (qc - 1) / 14 : 0;
      int cq = (qc > 0) ? (qc - 1) % 14 : 0;
      int rsw = (ql2 & 7) << 4;
      #pragma unroll
      for (int nf = 0; nf < 13; ++nf) {
        int k = 16 * nf + fr;
        float s;
        if (k < 197) {
          int fv  = (qc == 0 || k == 0) ? 0 : ((k - 1) / 14 - gq + 15);
          int fh2 = (qc == 0 || k == 0) ? 0 : ((k - 1) % 14 - cq + 15);
          float pv = bf16tof(*(const u16*)(PvB + (((ql2 * 64 + fv) * 2) ^ rsw)));
          float ph = bf16tof(*(const u16*)(PvB + (((ql2 * 64 + 30 + fh2) * 2) ^ rsw)));
          s = (sacc[nf][r] + pv + ph) * SCALE;
        } else s = -1e30f;
        ex[nf][r] = s;
        mrow[r] = fmaxf(mrow[r], s);
      }
    }
    #pragma unroll
    for (int r = 0; r < 4; ++r)
      #pragma unroll
      for (int mk = 1; mk < 16; mk <<= 1) mrow[r] = fmaxf(mrow[r], __shfl_xor(mrow[r], mk));
    float sum[4] = {0.f, 0.f, 0.f, 0.f};
    #pragma unroll
    for (int nf = 0; nf < 13; ++nf)
      #pragma unroll
      for (int r = 0; r < 4; ++r) {
        ex[nf][r] = __expf(ex[nf][r] - mrow[r]);
        sum[r] += ex[nf][r];
      }
    float inv[4];
    #pragma unroll
    for (int r = 0; r < 4; ++r) {
      #pragma unroll
      for (int mk = 1; mk < 16; mk <<= 1) sum[r] += __shfl_xor(sum[r], mk);
      inv[r] = 1.f / sum[r];
    }
    #pragma unroll
    for (int nf = 0; nf < 13; ++nf) {
      pk01[nf] = (unsigned)bf16rn(ex[nf][0] * inv[0]) |
                 ((unsigned)bf16rn(ex[nf][1] * inv[1]) << 16);
      pk23[nf] = (unsigned)bf16rn(ex[nf][2] * inv[2]) |
                 ((unsigned)bf16rn(ex[nf][3] * inv[3]) << 16);
    }
  } else {
    #pragma unroll
    for (int nf = 0; nf < 13; ++nf) { pk01[nf] = 0; pk23[nf] = 0; }
  }
  __syncthreads();   // B4: K + PvPh reads done everywhere

  int qf = w & 3, hs2 = w >> 2;
  int prow = 16 * qf + fr;
  int pswz = ((prow & 7) ^ ((prow >> 3) & 7)) << 4;
  int vrow0 = 32 * hs2 + fr, vrow1 = vrow0 + 16;
  int vswz0 = ((vrow0 & 7) ^ ((vrow0 >> 3) & 7)) << 4;
  int vswz1 = ((vrow1 & 7) ^ ((vrow1 >> 3) & 7)) << 4;

  // TvL staging (overlays PvPh rows 64..123 -- dead after B4)
  for (int i = t; i < 3840; i += 512) {
    int row = i >> 6, d = i & 63;
    float vv = (row < 30) ? tvv[row * 64 + d] : tvh[(row - 30) * 64 + d];
    TvL[i] = bf16rn(vv);
  }

  for (int p = 0; p < 2; ++p) {
    // P-write for q-half p by owner waves
    if ((w >> 2) == p) {
      int rbase = 16 * (w & 3);
      #pragma unroll
      for (int nf = 0; nf < 14; ++nf)
        #pragma unroll
        for (int r = 0; r < 4; ++r) {
          int k = 16 * nf + fr;
          int pr = rbase + 4 * fq + r;
          u16 val = 0;
          if (nf < 13) {
            unsigned pk = (r < 2) ? pk01[nf] : pk23[nf];
            val = (r & 1) ? (u16)(pk >> 16) : (u16)(pk & 0xFFFF);
          }
          int byte = (pr * 224 + k) * 2; byte ^= (((pr & 7) ^ ((pr >> 3) & 7)) << 4);
          *(u16*)(Phi + byte) = val;
        }
    }
    __syncthreads();   // B5 / B7

    // AV (hi-only): wave (qf, hs2) -> q rows 16qf.., d frags {2hs2, 2hs2+1}
    f32x4 ov0 = {}, ov1 = {};
    #pragma unroll
    for (int ks = 0; ks < 7; ++ks) {
      int co = 64 * ks + 16 * fq;
      bf16x8 pah = *(const bf16x8*)(Phi + ((prow * 448 + co) ^ pswz));
      bf16x8 v0  = *(const bf16x8*)(Vh + ((vrow0 * 448 + co) ^ vswz0));
      bf16x8 v1  = *(const bf16x8*)(Vh + ((vrow1 * 448 + co) ^ vswz1));
      ov0 = __builtin_amdgcn_mfma_f32_16x16x32_bf16(pah, v0, ov0, 0, 0, 0);
      ov1 = __builtin_amdgcn_mfma_f32_16x16x32_bf16(pah, v1, ov1, 0, 0, 0);
    }

    // bucket sums Bv/Bh via VALU over P in LDS
    for (int s = t; s < 1920; s += 512) {
      int q = s / 30, rem = s % 30;
      int isH = rem >= 15 ? 1 : 0, a = rem - 15 * isH;
      int sw = ((q & 7) ^ ((q >> 3) & 7)) << 4;
      float acc = 0.f;
      if (a == 14) {
        acc = bf16tof(*(const u16*)(Phi + (((q * 224 + 0) * 2) ^ sw)));
      } else if (!isH) {
        int k0b = 1 + 14 * a;
        #pragma unroll
        for (int j = 0; j < 14; ++j)
          acc += bf16tof(*(const u16*)(Phi + (((q * 224 + k0b + j) * 2) ^ sw)));
      } else {
        #pragma unroll
        for (int i2 = 0; i2 < 14; ++i2)
          acc += bf16tof(*(const u16*)(Phi + (((q * 224 + 1 + a + 14 * i2) * 2) ^ sw)));
      }
      BvBh[q * 32 + 16 * isH + a] = acc;
    }
    __syncthreads();   // B6 / B8

    // epilogue for q-half p
    #pragma unroll
    for (int r = 0; r < 4; ++r) {
      int qlocal = 16 * qf + 4 * fq + r;
      int qg = q0 + 64 * p + qlocal;
      if (qg >= NN) continue;
      float o0 = ov0[r], o1 = ov1[r];
      int d0 = 32 * hs2 + fr, d1 = d0 + 16;
      if (qg == 0) {
        float sv = 0.f, sh = 0.f;
        #pragma unroll
        for (int a = 0; a < 15; ++a) {
          sv += BvBh[qlocal * 32 + a];
          sh += BvBh[qlocal * 32 + 16 + a];
        }
        o0 += sv * bf16tof(TvL[d0]) + sh * bf16tof(TvL[1920 + d0]);
        o1 += sv * bf16tof(TvL[d1]) + sh * bf16tof(TvL[1920 + d1]);
      } else {
        int gq = (qg - 1) / 14, cq = (qg - 1) % 14;
        float cv = BvBh[qlocal * 32 + 14], ch = BvBh[qlocal * 32 + 30];
        o0 += cv * bf16tof(TvL[d0]) + ch * bf16tof(TvL[1920 + d0]);
        o1 += cv * bf16tof(TvL[d1]) + ch * bf16tof(TvL[1920 + d1]);
        for (int a = 0; a < 14; ++a) {
          float cva = BvBh[qlocal * 32 + a], cha = BvBh[qlocal * 32 + 16 + a];
          int rv = (a + 15 - gq) * 64, rh = (a + 15 - cq) * 64;
          o0 += cva * bf16tof(TvL[rv + d0]) + cha * bf16tof(TvL[1920 + rh + d0]);
          o1 += cva * bf16tof(TvL[rv + d1]) + cha * bf16tof(TvL[1920 + rh + d1]);
        }
      }
      size_t ob = (size_t)(b * NN + qg) * CC + h * DD;
      u16 hh, ll;
      split_bf16(o0, hh, ll); ohi[ob + d0] = hh; olo[ob + d0] = ll;
      split_bf16(o1, hh, ll); ohi[ob + d1] = hh; olo[ob + d1] = ll;
    }
  }
}

// ---------------------------------------------------------------------------
// Workspace (u16 units, 135.7 MB):
//   qkvhi 24,207,360 | qkvlo 24,207,360 | xhi/xlo 2x8,069,120 (reused ohi/olo)
//   weffhi/lo 2x1,228,800 | wphi/lo 2x409,600 | tabKhi/lo 2x4,096
// ---------------------------------------------------------------------------
extern "C" void kernel_launch(void* const* d_in, const int* in_sizes, int n_in,
                              void* d_out, int out_size, void* d_ws, size_t ws_size,
                              hipStream_t stream) {
  (void)in_sizes; (void)n_in; (void)out_size; (void)ws_size;
  const float* x     = (const float*)d_in[0];
  const float* w_qkv = (const float*)d_in[1];
  const float* b_qkv = (const float*)d_in[2];
  const float* la    = (const float*)d_in[3];
  const float* lb    = (const float*)d_in[4];
  const float* tkv   = (const float*)d_in[5];
  const float* tkh   = (const float*)d_in[6];
  const float* tvv   = (const float*)d_in[7];
  const float* tvh   = (const float*)d_in[8];
  const float* wp    = (const float*)d_in[9];
  const float* b_p   = (const float*)d_in[10];

  u16* qkvhi  = (u16*)d_ws;
  u16* qkvlo  = qkvhi + (size_t)24207360;
  u16* xhi    = qkvlo + (size_t)24207360;
  u16* xlo    = xhi + (size_t)8069120;
  u16* ohi    = xhi;                       // alias (x splits dead after gemm1)
  u16* olo    = xlo;
  u16* weffhi = xlo + (size_t)8069120;
  u16* wefflo = weffhi + (size_t)1228800;
  u16* wphi   = wefflo + (size_t)1228800;
  u16* wplo   = wphi + (size_t)409600;
  u16* tabKhi = wplo + (size_t)409600;
  u16* tabKlo = tabKhi + (size_t)4096;

  k_weff<<<(C3 * CC) / 256, 256, 0, stream>>>(w_qkv, la, lb, weffhi, wefflo);
  k_cvtw<<<(CC * CC) / 256, 256, 0, stream>>>(wp, wphi, wplo);
  k_prep<<<1, 256, 0, stream>>>(tkv, tkh, tabKhi, tabKlo);
  int n4x = (MTOT * CC) / 4;
  k_cvt<<<(n4x + 255) / 256, 256, 0, stream>>>(x, xhi, xlo, n4x);

  // qkv = x @ weff^T + b_qkv -> split bf16 output
  dim3 g1((MTOT + 127) / 128, C3 / 128);
  k_gemm_mfma<1><<<g1, dim3(256), 0, stream>>>(xhi, xlo, weffhi, wefflo, b_qkv,
                                               nullptr, qkvhi, qkvlo, MTOT, C3);

  // fused attention -> ohi/olo split
  k_attn<<<dim3(BB * HH, 2), 512, 0, stream>>>(qkvhi, qkvlo, tabKhi, tabKlo,
                                               tvv, tvh, ohi, olo);

  // out = o @ perm3(w_proj)^T + b_proj
  dim3 g2((MTOT + 127) / 128, CC / 128);
  k_gemm_mfma<0><<<g2, dim3(256), 0, stream>>>(ohi, olo, wphi, wplo, b_p,
                                               (float*)d_out, nullptr, nullptr, MTOT, CC);
}

// Round 7
// 374.658 us; speedup vs baseline: 1.1169x; 1.1169x over previous
//
#include <hip/hip_runtime.h>
#include <math.h>

#define BB 64
#define NN 197
#define HH 10
#define DD 64
#define CC 640
#define C3 1920
#define LR 64
#define MTOT (BB*NN)          // 12608
#define SCALE 0.125f

typedef unsigned short u16;
typedef __bf16 bf16x8 __attribute__((ext_vector_type(8)));
typedef float f32x4 __attribute__((ext_vector_type(4)));

__device__ __forceinline__ void split_bf16(float f, u16& hi, u16& lo) {
  unsigned u = __float_as_uint(f);
  unsigned r = u + 0x7FFF + ((u >> 16) & 1);
  u16 hb = (u16)(r >> 16);
  float fh = __uint_as_float((unsigned)hb << 16);
  float dl = f - fh;
  unsigned u2 = __float_as_uint(dl);
  unsigned r2 = u2 + 0x7FFF + ((u2 >> 16) & 1);
  hi = hb; lo = (u16)(r2 >> 16);
}

__device__ __forceinline__ u16 bf16rn(float f) {
  unsigned u = __float_as_uint(f);
  return (u16)((u + 0x7FFF + ((u >> 16) & 1)) >> 16);
}
__device__ __forceinline__ float bf16tof(u16 v) {
  return __uint_as_float((unsigned)v << 16);
}

// ---------------------------------------------------------------------------
// K1: w_eff = perm3(w_qkv + (lora_a @ lora_b)^T) -> bf16 hi/lo split
// ---------------------------------------------------------------------------
__global__ __launch_bounds__(256) void k_weff(
    const float* __restrict__ w_qkv, const float* __restrict__ la,
    const float* __restrict__ lb, u16* __restrict__ whi, u16* __restrict__ wlo) {
  int idx = blockIdx.x * 256 + threadIdx.x;      // covers 1920*640
  int i = idx / CC, j = idx % CC;
  int src = 3 * (i % CC) + (i / CC);
  float acc = w_qkv[(size_t)src * CC + j];
  const float* laj = la + (size_t)j * LR;
  const float* lbs = lb + src;
  #pragma unroll 8
  for (int r = 0; r < LR; ++r) acc = fmaf(laj[r], lbs[(size_t)r * C3], acc);
  u16 h, l; split_bf16(acc, h, l);
  whi[idx] = h; wlo[idx] = l;
}

// fp32 -> bf16 hi/lo split
__global__ __launch_bounds__(256) void k_cvt(
    const float* __restrict__ in, u16* __restrict__ hi, u16* __restrict__ lo, int n4) {
  int i = blockIdx.x * 256 + threadIdx.x;
  if (i >= n4) return;
  float4 v = ((const float4*)in)[i];
  float f[4] = {v.x, v.y, v.z, v.w};
  ushort4 H, L;
  u16 hh, ll;
  split_bf16(f[0], hh, ll); H.x = hh; L.x = ll;
  split_bf16(f[1], hh, ll); H.y = hh; L.y = ll;
  split_bf16(f[2], hh, ll); H.z = hh; L.z = ll;
  split_bf16(f[3], hh, ll); H.w = hh; L.w = ll;
  ((ushort4*)hi)[i] = H;
  ((ushort4*)lo)[i] = L;
}

__device__ __forceinline__ int perm640(int i) {
  return (i < 214) ? 3 * i : (i < 427 ? 3 * (i - 214) + 1 : 3 * (i - 427) + 2);
}

__global__ __launch_bounds__(256) void k_cvtw(
    const float* __restrict__ wp, u16* __restrict__ hi, u16* __restrict__ lo) {
  int idx = blockIdx.x * 256 + threadIdx.x;      // covers 640*640
  int i = idx / CC, j = idx % CC;
  float v = wp[(size_t)perm640(i) * CC + j];
  u16 h, l; split_bf16(v, h, l);
  hi[idx] = h; lo[idx] = l;
}

// tabK: rows 0..29 tkv, 30..59 tkh, 60..63 zero -> bf16 hi/lo [64][64]
__global__ __launch_bounds__(256) void k_prep(
    const float* __restrict__ tkv, const float* __restrict__ tkh,
    u16* __restrict__ thi, u16* __restrict__ tlo) {
  for (int idx = threadIdx.x; idx < 4096; idx += 256) {
    int row = idx >> 6, d = idx & 63;
    float v = row < 30 ? tkv[row * 64 + d] : (row < 60 ? tkh[(row - 30) * 64 + d] : 0.f);
    u16 hh, ll; split_bf16(v, hh, ll);
    thi[idx] = hh; tlo[idx] = ll;
  }
}

// ---------------------------------------------------------------------------
// Split-bf16 MFMA GEMM, fused 3-pass (hh, lh, hl per k-step). 128x128, BK=64.
// ---------------------------------------------------------------------------
template<int OSPLIT>
__global__ __launch_bounds__(256) void k_gemm_mfma(
    const u16* __restrict__ Ahi, const u16* __restrict__ Alo,
    const u16* __restrict__ Bhi, const u16* __restrict__ Blo,
    const float* __restrict__ bias, float* __restrict__ Cc,
    u16* __restrict__ Chi, u16* __restrict__ Clo,
    int M, int Nc) {
  __shared__ u16 AsH[128][64];
  __shared__ u16 AsL[128][64];
  __shared__ u16 BsH[128][64];
  __shared__ u16 BsL[128][64];
  int t = threadIdx.x, w = t >> 6, l = t & 63;
  int m0 = blockIdx.x * 128, n0 = blockIdx.y * 128;
  int wr = w >> 1, wc = w & 1;
  f32x4 acc[4][4] = {};
  int srow = l >> 3;
  int scol = (l & 7) * 8;

  for (int k0 = 0; k0 < 640; k0 += 64) {
    #pragma unroll
    for (int j = 0; j < 4; ++j) {
      int row = 32 * w + 8 * j + srow;
      int ga = m0 + row; if (ga >= M) ga = M - 1;
      size_t offA = (size_t)ga * 640 + k0 + scol;
      size_t offB = (size_t)(n0 + row) * 640 + k0 + scol;
      __builtin_amdgcn_global_load_lds(
          (const __attribute__((address_space(1))) void*)(Ahi + offA),
          (__attribute__((address_space(3))) void*)(&AsH[32 * w + 8 * j][0]), 16, 0, 0);
      __builtin_amdgcn_global_load_lds(
          (const __attribute__((address_space(1))) void*)(Alo + offA),
          (__attribute__((address_space(3))) void*)(&AsL[32 * w + 8 * j][0]), 16, 0, 0);
      __builtin_amdgcn_global_load_lds(
          (const __attribute__((address_space(1))) void*)(Bhi + offB),
          (__attribute__((address_space(3))) void*)(&BsH[32 * w + 8 * j][0]), 16, 0, 0);
      __builtin_amdgcn_global_load_lds(
          (const __attribute__((address_space(1))) void*)(Blo + offB),
          (__attribute__((address_space(3))) void*)(&BsL[32 * w + 8 * j][0]), 16, 0, 0);
    }
    __syncthreads();
    int fr = l & 15, fq = l >> 4;
    #pragma unroll
    for (int ks = 0; ks < 2; ++ks) {
      bf16x8 ah[4], al[4], bh[4], bl[4];
      #pragma unroll
      for (int mi = 0; mi < 4; ++mi) {
        ah[mi] = *(const bf16x8*)&AsH[wr * 64 + 16 * mi + fr][ks * 32 + fq * 8];
        al[mi] = *(const bf16x8*)&AsL[wr * 64 + 16 * mi + fr][ks * 32 + fq * 8];
        bh[mi] = *(const bf16x8*)&BsH[wc * 64 + 16 * mi + fr][ks * 32 + fq * 8];
        bl[mi] = *(const bf16x8*)&BsL[wc * 64 + 16 * mi + fr][ks * 32 + fq * 8];
      }
      #pragma unroll
      for (int mi = 0; mi < 4; ++mi)
        #pragma unroll
        for (int ni = 0; ni < 4; ++ni) {
          acc[mi][ni] = __builtin_amdgcn_mfma_f32_16x16x32_bf16(ah[mi], bh[ni], acc[mi][ni], 0, 0, 0);
          acc[mi][ni] = __builtin_amdgcn_mfma_f32_16x16x32_bf16(al[mi], bh[ni], acc[mi][ni], 0, 0, 0);
          acc[mi][ni] = __builtin_amdgcn_mfma_f32_16x16x32_bf16(ah[mi], bl[ni], acc[mi][ni], 0, 0, 0);
        }
    }
    __syncthreads();
  }

  int fr = l & 15, fq = l >> 4;
  #pragma unroll
  for (int mi = 0; mi < 4; ++mi) {
    #pragma unroll
    for (int ni = 0; ni < 4; ++ni) {
      int col = n0 + wc * 64 + 16 * ni + fr;
      float bv = bias[col];
      #pragma unroll
      for (int r = 0; r < 4; ++r) {
        int row = m0 + wr * 64 + 16 * mi + fq * 4 + r;
        if (row < M) {
          float val = acc[mi][ni][r] + bv;
          if (OSPLIT) {
            u16 hh, ll; split_bf16(val, hh, ll);
            Chi[(size_t)row * Nc + col] = hh;
            Clo[(size_t)row * Nc + col] = ll;
          } else {
            Cc[(size_t)row * Nc + col] = val;
          }
        }
      }
    }
  }
}

// ---------------------------------------------------------------------------
// Fused MFMA attention v3b: identical to v3 (round 6) except launch bounds
// (512,2): round 6's (512,4) forced VGPR=64 -> massive scratch spill
// (WRITE_SIZE 245 MB/dispatch). At 128 VGPR the HW still co-schedules
// 2 blocks/CU (LDS 79,872 x2 fits; 16 waves = 4/SIMD needs VGPR<=128).
// LDS overlays:
//   [0,34816)     K[272][64]u16 (hi then lo)  -> post-B4: Phi[64][224]u16
//   [34816,51200) PvPh[128][64]bf16 -> post-B5: BvBh[64][32]f32 + TvL[60][64]bf16
//   [51200,79872) Vhi[64][224]u16
// ---------------------------------------------------------------------------
__global__ __launch_bounds__(512, 2) void k_attn(
    const u16* __restrict__ qkvhi, const u16* __restrict__ qkvlo,
    const u16* __restrict__ tabKhi, const u16* __restrict__ tabKlo,
    const float* __restrict__ tvv, const float* __restrict__ tvh,
    u16* __restrict__ ohi, u16* __restrict__ olo) {
  __shared__ __align__(16) unsigned char LDS[79872];
  unsigned char* Ak  = LDS;                    // [272][64]u16
  unsigned char* Phi = LDS;                    // post-B4: [64][224]u16
  unsigned char* PvB = LDS + 34816;            // [128][64] bf16
  float* BvBh = (float*)(LDS + 34816);         // post-B5: [64][32] f32
  u16*   TvL  = (u16*)(LDS + 43008);           // [60][64] bf16
  unsigned char* Vh  = LDS + 51200;            // [64][224]u16

  int bh = blockIdx.x, b = bh / HH, h = bh % HH, qt = blockIdx.y;
  int t = threadIdx.x, w = t >> 6, l = t & 63;
  int fr = l & 15, fq = l >> 4;
  int q0 = 128 * qt;
  const size_t qbase = (size_t)(b * NN) * C3;

  // ---- K hi + tab hi glds (pre-swizzled source, linear dest) ----
  int kr = l >> 3;
  int chunk = ((l & 7) ^ (kr & 7)) * 8;
  for (int i = w; i < 26; i += 8) {
    int kk = 8 * i + kr; if (kk > 196) kk = 196;
    size_t src = qbase + (size_t)kk * C3 + CC + h * DD + chunk;
    __builtin_amdgcn_global_load_lds(
        (const __attribute__((address_space(1))) void*)(qkvhi + src),
        (__attribute__((address_space(3))) void*)(Ak + i * 1024), 16, 0, 0);
  }
  {
    int tr = 8 * w + kr;
    __builtin_amdgcn_global_load_lds(
        (const __attribute__((address_space(1))) void*)(tabKhi + tr * 64 + chunk),
        (__attribute__((address_space(3))) void*)(Ak + 26624 + w * 1024), 16, 0, 0);
  }
  // ---- V^T hi staging (scatter, conflict-free swizzle) ----
  for (int idx = t; idx < 1576; idx += 512) {
    int k = idx >> 3, d0v = (idx & 7) * 8;
    size_t off = qbase + (size_t)k * C3 + 2 * CC + h * DD + d0v;
    uint4 vh4 = *(const uint4*)(qkvhi + off);
    u16 eh[8] = {(u16)vh4.x, (u16)(vh4.x >> 16), (u16)vh4.y, (u16)(vh4.y >> 16),
                 (u16)vh4.z, (u16)(vh4.z >> 16), (u16)vh4.w, (u16)(vh4.w >> 16)};
    #pragma unroll
    for (int jj = 0; jj < 8; ++jj) {
      int d = d0v + jj;
      int byte = (d * 224 + k) * 2; byte ^= (((d & 7) ^ ((d >> 3) & 7)) << 4);
      *(u16*)(Vh + byte) = eh[jj];
    }
  }
  for (int idx = t; idx < 64 * 27; idx += 512) {   // zero-pad cols 197..223
    int d = idx / 27, k = 197 + idx % 27;
    int byte = (d * 224 + k) * 2; byte ^= (((d & 7) ^ ((d >> 3) & 7)) << 4);
    *(u16*)(Vh + byte) = 0;
  }

  // ---- Q fragments ----
  bool active = (q0 + 16 * w) < NN;
  bf16x8 qh[2], ql_[2];
  {
    int qg = q0 + 16 * w + fr; int qc = qg > 196 ? 196 : qg;
    const u16* qr  = qkvhi + qbase + (size_t)qc * C3 + h * DD;
    const u16* qr2 = qkvlo + qbase + (size_t)qc * C3 + h * DD;
    qh[0]  = *(const bf16x8*)(qr + 8 * fq);
    qh[1]  = *(const bf16x8*)(qr + 32 + 8 * fq);
    ql_[0] = *(const bf16x8*)(qr2 + 8 * fq);
    ql_[1] = *(const bf16x8*)(qr2 + 32 + 8 * fq);
  }
  __syncthreads();   // B1

  // ---- S passes 1+2 vs Khi ----
  f32x4 sacc[17] = {};
  if (active) {
    #pragma unroll
    for (int ks = 0; ks < 2; ++ks)
      #pragma unroll
      for (int nf = 0; nf < 17; ++nf) {
        int row = 16 * nf + fr;
        int byte = row * 128 + 64 * ks + 16 * fq; byte ^= (row & 7) << 4;
        bf16x8 kf = *(const bf16x8*)(Ak + byte);
        sacc[nf] = __builtin_amdgcn_mfma_f32_16x16x32_bf16(qh[ks],  kf, sacc[nf], 0, 0, 0);
        sacc[nf] = __builtin_amdgcn_mfma_f32_16x16x32_bf16(ql_[ks], kf, sacc[nf], 0, 0, 0);
      }
  }
  __syncthreads();   // B2

  // ---- K lo + tab lo staging (overlay) ----
  for (int i = w; i < 26; i += 8) {
    int kk = 8 * i + kr; if (kk > 196) kk = 196;
    size_t src = qbase + (size_t)kk * C3 + CC + h * DD + chunk;
    __builtin_amdgcn_global_load_lds(
        (const __attribute__((address_space(1))) void*)(qkvlo + src),
        (__attribute__((address_space(3))) void*)(Ak + i * 1024), 16, 0, 0);
  }
  {
    int tr = 8 * w + kr;
    __builtin_amdgcn_global_load_lds(
        (const __attribute__((address_space(1))) void*)(tabKlo + tr * 64 + chunk),
        (__attribute__((address_space(3))) void*)(Ak + 26624 + w * 1024), 16, 0, 0);
  }
  __syncthreads();   // B3

  // ---- S pass 3 (qh . Klo), PvPh write, softmax, pack ----
  unsigned pk01[13], pk23[13];
  if (active) {
    #pragma unroll
    for (int ks = 0; ks < 2; ++ks)
      #pragma unroll
      for (int nf = 0; nf < 17; ++nf) {
        int row = 16 * nf + fr;
        int byte = row * 128 + 64 * ks + 16 * fq; byte ^= (row & 7) << 4;
        bf16x8 kf = *(const bf16x8*)(Ak + byte);
        sacc[nf] = __builtin_amdgcn_mfma_f32_16x16x32_bf16(qh[ks], kf, sacc[nf], 0, 0, 0);
      }
    // Pv/Ph (frags 13..16) -> LDS bf16 (wave-local rows, swz by row)
    #pragma unroll
    for (int nf = 13; nf < 17; ++nf)
      #pragma unroll
      for (int r = 0; r < 4; ++r) {
        int c = 16 * (nf - 13) + fr;
        if (c < 60) {
          int row = 16 * w + 4 * fq + r;
          int byte = (row * 64 + c) * 2; byte ^= (row & 7) << 4;
          *(u16*)(PvB + byte) = bf16rn(sacc[nf][r]);
        }
      }
    float ex[13][4];
    float mrow[4] = {-1e30f, -1e30f, -1e30f, -1e30f};
    #pragma unroll
    for (int r = 0; r < 4; ++r) {
      int ql2 = 16 * w + 4 * fq + r; int qg = q0 + ql2;
      int qc = qg > 196 ? 196 : qg;
      int gq = (qc > 0) ? (qc - 1) / 14 : 0;
      int cq = (qc > 0) ? (qc - 1) % 14 : 0;
      int rsw = (ql2 & 7) << 4;
      #pragma unroll
      for (int nf = 0; nf < 13; ++nf) {
        int k = 16 * nf + fr;
        float s;
        if (k < 197) {
          int fv  = (qc == 0 || k == 0) ? 0 : ((k - 1) / 14 - gq + 15);
          int fh2 = (qc == 0 || k == 0) ? 0 : ((k - 1) % 14 - cq + 15);
          float pv = bf16tof(*(const u16*)(PvB + (((ql2 * 64 + fv) * 2) ^ rsw)));
          float ph = bf16tof(*(const u16*)(PvB + (((ql2 * 64 + 30 + fh2) * 2) ^ rsw)));
          s = (sacc[nf][r] + pv + ph) * SCALE;
        } else s = -1e30f;
        ex[nf][r] = s;
        mrow[r] = fmaxf(mrow[r], s);
      }
    }
    #pragma unroll
    for (int r = 0; r < 4; ++r)
      #pragma unroll
      for (int mk = 1; mk < 16; mk <<= 1) mrow[r] = fmaxf(mrow[r], __shfl_xor(mrow[r], mk));
    float sum[4] = {0.f, 0.f, 0.f, 0.f};
    #pragma unroll
    for (int nf = 0; nf < 13; ++nf)
      #pragma unroll
      for (int r = 0; r < 4; ++r) {
        ex[nf][r] = __expf(ex[nf][r] - mrow[r]);
        sum[r] += ex[nf][r];
      }
    float inv[4];
    #pragma unroll
    for (int r = 0; r < 4; ++r) {
      #pragma unroll
      for (int mk = 1; mk < 16; mk <<= 1) sum[r] += __shfl_xor(sum[r], mk);
      inv[r] = 1.f / sum[r];
    }
    #pragma unroll
    for (int nf = 0; nf < 13; ++nf) {
      pk01[nf] = (unsigned)bf16rn(ex[nf][0] * inv[0]) |
                 ((unsigned)bf16rn(ex[nf][1] * inv[1]) << 16);
      pk23[nf] = (unsigned)bf16rn(ex[nf][2] * inv[2]) |
                 ((unsigned)bf16rn(ex[nf][3] * inv[3]) << 16);
    }
  } else {
    #pragma unroll
    for (int nf = 0; nf < 13; ++nf) { pk01[nf] = 0; pk23[nf] = 0; }
  }
  __syncthreads();   // B4: K + PvPh reads done everywhere

  int qf = w & 3, hs2 = w >> 2;
  int prow = 16 * qf + fr;
  int pswz = ((prow & 7) ^ ((prow >> 3) & 7)) << 4;
  int vrow0 = 32 * hs2 + fr, vrow1 = vrow0 + 16;
  int vswz0 = ((vrow0 & 7) ^ ((vrow0 >> 3) & 7)) << 4;
  int vswz1 = ((vrow1 & 7) ^ ((vrow1 >> 3) & 7)) << 4;

  // TvL staging (overlays PvPh rows 64..123 -- dead after B4)
  for (int i = t; i < 3840; i += 512) {
    int row = i >> 6, d = i & 63;
    float vv = (row < 30) ? tvv[row * 64 + d] : tvh[(row - 30) * 64 + d];
    TvL[i] = bf16rn(vv);
  }

  for (int p = 0; p < 2; ++p) {
    // P-write for q-half p by owner waves
    if ((w >> 2) == p) {
      int rbase = 16 * (w & 3);
      #pragma unroll
      for (int nf = 0; nf < 14; ++nf)
        #pragma unroll
        for (int r = 0; r < 4; ++r) {
          int k = 16 * nf + fr;
          int pr = rbase + 4 * fq + r;
          u16 val = 0;
          if (nf < 13) {
            unsigned pk = (r < 2) ? pk01[nf] : pk23[nf];
            val = (r & 1) ? (u16)(pk >> 16) : (u16)(pk & 0xFFFF);
          }
          int byte = (pr * 224 + k) * 2; byte ^= (((pr & 7) ^ ((pr >> 3) & 7)) << 4);
          *(u16*)(Phi + byte) = val;
        }
    }
    __syncthreads();   // B5 / B7

    // AV (hi-only): wave (qf, hs2) -> q rows 16qf.., d frags {2hs2, 2hs2+1}
    f32x4 ov0 = {}, ov1 = {};
    #pragma unroll
    for (int ks = 0; ks < 7; ++ks) {
      int co = 64 * ks + 16 * fq;
      bf16x8 pah = *(const bf16x8*)(Phi + ((prow * 448 + co) ^ pswz));
      bf16x8 v0  = *(const bf16x8*)(Vh + ((vrow0 * 448 + co) ^ vswz0));
      bf16x8 v1  = *(const bf16x8*)(Vh + ((vrow1 * 448 + co) ^ vswz1));
      ov0 = __builtin_amdgcn_mfma_f32_16x16x32_bf16(pah, v0, ov0, 0, 0, 0);
      ov1 = __builtin_amdgcn_mfma_f32_16x16x32_bf16(pah, v1, ov1, 0, 0, 0);
    }

    // bucket sums Bv/Bh via VALU over P in LDS
    for (int s = t; s < 1920; s += 512) {
      int q = s / 30, rem = s % 30;
      int isH = rem >= 15 ? 1 : 0, a = rem - 15 * isH;
      int sw = ((q & 7) ^ ((q >> 3) & 7)) << 4;
      float acc = 0.f;
      if (a == 14) {
        acc = bf16tof(*(const u16*)(Phi + (((q * 224 + 0) * 2) ^ sw)));
      } else if (!isH) {
        int k0b = 1 + 14 * a;
        #pragma unroll
        for (int j = 0; j < 14; ++j)
          acc += bf16tof(*(const u16*)(Phi + (((q * 224 + k0b + j) * 2) ^ sw)));
      } else {
        #pragma unroll
        for (int i2 = 0; i2 < 14; ++i2)
          acc += bf16tof(*(const u16*)(Phi + (((q * 224 + 1 + a + 14 * i2) * 2) ^ sw)));
      }
      BvBh[q * 32 + 16 * isH + a] = acc;
    }
    __syncthreads();   // B6 / B8

    // epilogue for q-half p
    #pragma unroll
    for (int r = 0; r < 4; ++r) {
      int qlocal = 16 * qf + 4 * fq + r;
      int qg = q0 + 64 * p + qlocal;
      if (qg >= NN) continue;
      float o0 = ov0[r], o1 = ov1[r];
      int d0 = 32 * hs2 + fr, d1 = d0 + 16;
      if (qg == 0) {
        float sv = 0.f, sh = 0.f;
        #pragma unroll
        for (int a = 0; a < 15; ++a) {
          sv += BvBh[qlocal * 32 + a];
          sh += BvBh[qlocal * 32 + 16 + a];
        }
        o0 += sv * bf16tof(TvL[d0]) + sh * bf16tof(TvL[1920 + d0]);
        o1 += sv * bf16tof(TvL[d1]) + sh * bf16tof(TvL[1920 + d1]);
      } else {
        int gq = (qg - 1) / 14, cq = (qg - 1) % 14;
        float cv = BvBh[qlocal * 32 + 14], ch = BvBh[qlocal * 32 + 30];
        o0 += cv * bf16tof(TvL[d0]) + ch * bf16tof(TvL[1920 + d0]);
        o1 += cv * bf16tof(TvL[d1]) + ch * bf16tof(TvL[1920 + d1]);
        for (int a = 0; a < 14; ++a) {
          float cva = BvBh[qlocal * 32 + a], cha = BvBh[qlocal * 32 + 16 + a];
          int rv = (a + 15 - gq) * 64, rh = (a + 15 - cq) * 64;
          o0 += cva * bf16tof(TvL[rv + d0]) + cha * bf16tof(TvL[1920 + rh + d0]);
          o1 += cva * bf16tof(TvL[rv + d1]) + cha * bf16tof(TvL[1920 + rh + d1]);
        }
      }
      size_t ob = (size_t)(b * NN + qg) * CC + h * DD;
      u16 hh, ll;
      split_bf16(o0, hh, ll); ohi[ob + d0] = hh; olo[ob + d0] = ll;
      split_bf16(o1, hh, ll); ohi[ob + d1] = hh; olo[ob + d1] = ll;
    }
  }
}

// ---------------------------------------------------------------------------
// Workspace (u16 units, 135.7 MB):
//   qkvhi 24,207,360 | qkvlo 24,207,360 | xhi/xlo 2x8,069,120 (reused ohi/olo)
//   weffhi/lo 2x1,228,800 | wphi/lo 2x409,600 | tabKhi/lo 2x4,096
// ---------------------------------------------------------------------------
extern "C" void kernel_launch(void* const* d_in, const int* in_sizes, int n_in,
                              void* d_out, int out_size, void* d_ws, size_t ws_size,
                              hipStream_t stream) {
  (void)in_sizes; (void)n_in; (void)out_size; (void)ws_size;
  const float* x     = (const float*)d_in[0];
  const float* w_qkv = (const float*)d_in[1];
  const float* b_qkv = (const float*)d_in[2];
  const float* la    = (const float*)d_in[3];
  const float* lb    = (const float*)d_in[4];
  const float* tkv   = (const float*)d_in[5];
  const float* tkh   = (const float*)d_in[6];
  const float* tvv   = (const float*)d_in[7];
  const float* tvh   = (const float*)d_in[8];
  const float* wp    = (const float*)d_in[9];
  const float* b_p   = (const float*)d_in[10];

  u16* qkvhi  = (u16*)d_ws;
  u16* qkvlo  = qkvhi + (size_t)24207360;
  u16* xhi    = qkvlo + (size_t)24207360;
  u16* xlo    = xhi + (size_t)8069120;
  u16* ohi    = xhi;                       // alias (x splits dead after gemm1)
  u16* olo    = xlo;
  u16* weffhi = xlo + (size_t)8069120;
  u16* wefflo = weffhi + (size_t)1228800;
  u16* wphi   = wefflo + (size_t)1228800;
  u16* wplo   = wphi + (size_t)409600;
  u16* tabKhi = wplo + (size_t)409600;
  u16* tabKlo = tabKhi + (size_t)4096;

  k_weff<<<(C3 * CC) / 256, 256, 0, stream>>>(w_qkv, la, lb, weffhi, wefflo);
  k_cvtw<<<(CC * CC) / 256, 256, 0, stream>>>(wp, wphi, wplo);
  k_prep<<<1, 256, 0, stream>>>(tkv, tkh, tabKhi, tabKlo);
  int n4x = (MTOT * CC) / 4;
  k_cvt<<<(n4x + 255) / 256, 256, 0, stream>>>(x, xhi, xlo, n4x);

  // qkv = x @ weff^T + b_qkv -> split bf16 output
  dim3 g1((MTOT + 127) / 128, C3 / 128);
  k_gemm_mfma<1><<<g1, dim3(256), 0, stream>>>(xhi, xlo, weffhi, wefflo, b_qkv,
                                               nullptr, qkvhi, qkvlo, MTOT, C3);

  // fused attention -> ohi/olo split
  k_attn<<<dim3(BB * HH, 2), 512, 0, stream>>>(qkvhi, qkvlo, tabKhi, tabKlo,
                                               tvv, tvh, ohi, olo);

  // out = o @ perm3(w_proj)^T + b_proj
  dim3 g2((MTOT + 127) / 128, CC / 128);
  k_gemm_mfma<0><<<g2, dim3(256), 0, stream>>>(ohi, olo, wphi, wplo, b_p,
                                               (float*)d_out, nullptr, nullptr, MTOT, CC);
}

// Round 8
// 364.508 us; speedup vs baseline: 1.1480x; 1.0278x over previous
//
#include <hip/hip_runtime.h>
#include <math.h>

#define BB 64
#define NN 197
#define HH 10
#define DD 64
#define CC 640
#define C3 1920
#define LR 64
#define MTOT (BB*NN)          // 12608
#define SCALE 0.125f

typedef unsigned short u16;
typedef __bf16 bf16x8 __attribute__((ext_vector_type(8)));
typedef float f32x4 __attribute__((ext_vector_type(4)));

__device__ __forceinline__ void split_bf16(float f, u16& hi, u16& lo) {
  unsigned u = __float_as_uint(f);
  unsigned r = u + 0x7FFF + ((u >> 16) & 1);
  u16 hb = (u16)(r >> 16);
  float fh = __uint_as_float((unsigned)hb << 16);
  float dl = f - fh;
  unsigned u2 = __float_as_uint(dl);
  unsigned r2 = u2 + 0x7FFF + ((u2 >> 16) & 1);
  hi = hb; lo = (u16)(r2 >> 16);
}

__device__ __forceinline__ u16 bf16rn(float f) {
  unsigned u = __float_as_uint(f);
  return (u16)((u + 0x7FFF + ((u >> 16) & 1)) >> 16);
}
__device__ __forceinline__ float bf16tof(u16 v) {
  return __uint_as_float((unsigned)v << 16);
}

// ---------------------------------------------------------------------------
// K1: w_eff = perm3(w_qkv + (lora_a @ lora_b)^T) -> bf16 hi/lo split
// ---------------------------------------------------------------------------
__global__ __launch_bounds__(256) void k_weff(
    const float* __restrict__ w_qkv, const float* __restrict__ la,
    const float* __restrict__ lb, u16* __restrict__ whi, u16* __restrict__ wlo) {
  int idx = blockIdx.x * 256 + threadIdx.x;      // covers 1920*640
  int i = idx / CC, j = idx % CC;
  int src = 3 * (i % CC) + (i / CC);
  float acc = w_qkv[(size_t)src * CC + j];
  const float* laj = la + (size_t)j * LR;
  const float* lbs = lb + src;
  #pragma unroll 8
  for (int r = 0; r < LR; ++r) acc = fmaf(laj[r], lbs[(size_t)r * C3], acc);
  u16 h, l; split_bf16(acc, h, l);
  whi[idx] = h; wlo[idx] = l;
}

// fp32 -> bf16 hi/lo split
__global__ __launch_bounds__(256) void k_cvt(
    const float* __restrict__ in, u16* __restrict__ hi, u16* __restrict__ lo, int n4) {
  int i = blockIdx.x * 256 + threadIdx.x;
  if (i >= n4) return;
  float4 v = ((const float4*)in)[i];
  float f[4] = {v.x, v.y, v.z, v.w};
  ushort4 H, L;
  u16 hh, ll;
  split_bf16(f[0], hh, ll); H.x = hh; L.x = ll;
  split_bf16(f[1], hh, ll); H.y = hh; L.y = ll;
  split_bf16(f[2], hh, ll); H.z = hh; L.z = ll;
  split_bf16(f[3], hh, ll); H.w = hh; L.w = ll;
  ((ushort4*)hi)[i] = H;
  ((ushort4*)lo)[i] = L;
}

__device__ __forceinline__ int perm640(int i) {
  return (i < 214) ? 3 * i : (i < 427 ? 3 * (i - 214) + 1 : 3 * (i - 427) + 2);
}

__global__ __launch_bounds__(256) void k_cvtw(
    const float* __restrict__ wp, u16* __restrict__ hi, u16* __restrict__ lo) {
  int idx = blockIdx.x * 256 + threadIdx.x;      // covers 640*640
  int i = idx / CC, j = idx % CC;
  float v = wp[(size_t)perm640(i) * CC + j];
  u16 h, l; split_bf16(v, h, l);
  hi[idx] = h; lo[idx] = l;
}

// tabK: rows 0..29 tkv, 30..59 tkh, 60..63 zero -> bf16 hi/lo [64][64]
__global__ __launch_bounds__(256) void k_prep(
    const float* __restrict__ tkv, const float* __restrict__ tkh,
    u16* __restrict__ thi, u16* __restrict__ tlo) {
  for (int idx = threadIdx.x; idx < 4096; idx += 256) {
    int row = idx >> 6, d = idx & 63;
    float v = row < 30 ? tkv[row * 64 + d] : (row < 60 ? tkh[(row - 30) * 64 + d] : 0.f);
    u16 hh, ll; split_bf16(v, hh, ll);
    thi[idx] = hh; tlo[idx] = ll;
  }
}

// ---------------------------------------------------------------------------
// Split-bf16 MFMA GEMM, fused 3-pass (hh, lh, hl per k-step). 128x128, BK=64.
// ---------------------------------------------------------------------------
template<int OSPLIT>
__global__ __launch_bounds__(256) void k_gemm_mfma(
    const u16* __restrict__ Ahi, const u16* __restrict__ Alo,
    const u16* __restrict__ Bhi, const u16* __restrict__ Blo,
    const float* __restrict__ bias, float* __restrict__ Cc,
    u16* __restrict__ Chi, u16* __restrict__ Clo,
    int M, int Nc) {
  __shared__ u16 AsH[128][64];
  __shared__ u16 AsL[128][64];
  __shared__ u16 BsH[128][64];
  __shared__ u16 BsL[128][64];
  int t = threadIdx.x, w = t >> 6, l = t & 63;
  int m0 = blockIdx.x * 128, n0 = blockIdx.y * 128;
  int wr = w >> 1, wc = w & 1;
  f32x4 acc[4][4] = {};
  int srow = l >> 3;
  int scol = (l & 7) * 8;

  for (int k0 = 0; k0 < 640; k0 += 64) {
    #pragma unroll
    for (int j = 0; j < 4; ++j) {
      int row = 32 * w + 8 * j + srow;
      int ga = m0 + row; if (ga >= M) ga = M - 1;
      size_t offA = (size_t)ga * 640 + k0 + scol;
      size_t offB = (size_t)(n0 + row) * 640 + k0 + scol;
      __builtin_amdgcn_global_load_lds(
          (const __attribute__((address_space(1))) void*)(Ahi + offA),
          (__attribute__((address_space(3))) void*)(&AsH[32 * w + 8 * j][0]), 16, 0, 0);
      __builtin_amdgcn_global_load_lds(
          (const __attribute__((address_space(1))) void*)(Alo + offA),
          (__attribute__((address_space(3))) void*)(&AsL[32 * w + 8 * j][0]), 16, 0, 0);
      __builtin_amdgcn_global_load_lds(
          (const __attribute__((address_space(1))) void*)(Bhi + offB),
          (__attribute__((address_space(3))) void*)(&BsH[32 * w + 8 * j][0]), 16, 0, 0);
      __builtin_amdgcn_global_load_lds(
          (const __attribute__((address_space(1))) void*)(Blo + offB),
          (__attribute__((address_space(3))) void*)(&BsL[32 * w + 8 * j][0]), 16, 0, 0);
    }
    __syncthreads();
    int fr = l & 15, fq = l >> 4;
    #pragma unroll
    for (int ks = 0; ks < 2; ++ks) {
      bf16x8 ah[4], al[4], bh[4], bl[4];
      #pragma unroll
      for (int mi = 0; mi < 4; ++mi) {
        ah[mi] = *(const bf16x8*)&AsH[wr * 64 + 16 * mi + fr][ks * 32 + fq * 8];
        al[mi] = *(const bf16x8*)&AsL[wr * 64 + 16 * mi + fr][ks * 32 + fq * 8];
        bh[mi] = *(const bf16x8*)&BsH[wc * 64 + 16 * mi + fr][ks * 32 + fq * 8];
        bl[mi] = *(const bf16x8*)&BsL[wc * 64 + 16 * mi + fr][ks * 32 + fq * 8];
      }
      #pragma unroll
      for (int mi = 0; mi < 4; ++mi)
        #pragma unroll
        for (int ni = 0; ni < 4; ++ni) {
          acc[mi][ni] = __builtin_amdgcn_mfma_f32_16x16x32_bf16(ah[mi], bh[ni], acc[mi][ni], 0, 0, 0);
          acc[mi][ni] = __builtin_amdgcn_mfma_f32_16x16x32_bf16(al[mi], bh[ni], acc[mi][ni], 0, 0, 0);
          acc[mi][ni] = __builtin_amdgcn_mfma_f32_16x16x32_bf16(ah[mi], bl[ni], acc[mi][ni], 0, 0, 0);
        }
    }
    __syncthreads();
  }

  int fr = l & 15, fq = l >> 4;
  #pragma unroll
  for (int mi = 0; mi < 4; ++mi) {
    #pragma unroll
    for (int ni = 0; ni < 4; ++ni) {
      int col = n0 + wc * 64 + 16 * ni + fr;
      float bv = bias[col];
      #pragma unroll
      for (int r = 0; r < 4; ++r) {
        int row = m0 + wr * 64 + 16 * mi + fq * 4 + r;
        if (row < M) {
          float val = acc[mi][ni][r] + bv;
          if (OSPLIT) {
            u16 hh, ll; split_bf16(val, hh, ll);
            Chi[(size_t)row * Nc + col] = hh;
            Clo[(size_t)row * Nc + col] = ll;
          } else {
            Cc[(size_t)row * Nc + col] = val;
          }
        }
      }
    }
  }
}

// ---------------------------------------------------------------------------
// Fused MFMA attention v4: 512 thr, q-tile 128, LDS 71,680 B (-> 2 blocks/CU).
// Changes vs v3b: (1) rel-v epilogue moved to MFMA: W[64q][64t]bf16 built from
// bucket sums (shift embedded), out_rel = W @ TvT (TvT[64d][64t] = transposed
// tables); kills the ~450-FMA/670-LDS-read fp32 shift-gather.
// (2) PvPh overlays the K region after a new post-pass-3 barrier (B3.5);
// BvBh stored bf16 in the Phi spare. LDS map:
//   R1 @0 [34816]: Ak[272][64]u16 -> (B3.5) PvB[128][60]bf16 (stride 120B)
//                  -> (B4, per-p) Phi[64][224]u16 swz; W[64][64] @0 post-AV;
//                  BvBh[64][32]bf16 @28672
//   @34816: Vh[64][224]u16 swz (28672)
//   @63488: TvT[64][64]bf16 swz (8192)
// ---------------------------------------------------------------------------
__global__ __launch_bounds__(512, 2) void k_attn(
    const u16* __restrict__ qkvhi, const u16* __restrict__ qkvlo,
    const u16* __restrict__ tabKhi, const u16* __restrict__ tabKlo,
    const float* __restrict__ tvv, const float* __restrict__ tvh,
    u16* __restrict__ ohi, u16* __restrict__ olo) {
  __shared__ __align__(16) unsigned char LDS[71680];
  unsigned char* Ak  = LDS;
  unsigned char* PvB = LDS;
  unsigned char* Phi = LDS;
  unsigned char* Wb  = LDS;
  u16* BvBh = (u16*)(LDS + 28672);
  unsigned char* Vh  = LDS + 34816;
  unsigned char* TvT = LDS + 63488;

  int bh = blockIdx.x, b = bh / HH, h = bh % HH, qt = blockIdx.y;
  int t = threadIdx.x, w = t >> 6, l = t & 63;
  int fr = l & 15, fq = l >> 4;
  int q0 = 128 * qt;
  const size_t qbase = (size_t)(b * NN) * C3;

  // ---- phase 1: K hi + tab hi (glds, pre-swizzled source) ----
  int kr = l >> 3;
  int chunk = ((l & 7) ^ (kr & 7)) * 8;
  for (int i = w; i < 26; i += 8) {
    int kk = 8 * i + kr; if (kk > 196) kk = 196;
    size_t src = qbase + (size_t)kk * C3 + CC + h * DD + chunk;
    __builtin_amdgcn_global_load_lds(
        (const __attribute__((address_space(1))) void*)(qkvhi + src),
        (__attribute__((address_space(3))) void*)(Ak + i * 1024), 16, 0, 0);
  }
  {
    int tr = 8 * w + kr;
    __builtin_amdgcn_global_load_lds(
        (const __attribute__((address_space(1))) void*)(tabKhi + tr * 64 + chunk),
        (__attribute__((address_space(3))) void*)(Ak + 26624 + w * 1024), 16, 0, 0);
  }
  // ---- V^T hi (d-major [64][224], conflict-free swizzle) ----
  for (int idx = t; idx < 1576; idx += 512) {
    int k = idx >> 3, d0v = (idx & 7) * 8;
    size_t off = qbase + (size_t)k * C3 + 2 * CC + h * DD + d0v;
    uint4 vh4 = *(const uint4*)(qkvhi + off);
    u16 eh[8] = {(u16)vh4.x, (u16)(vh4.x >> 16), (u16)vh4.y, (u16)(vh4.y >> 16),
                 (u16)vh4.z, (u16)(vh4.z >> 16), (u16)vh4.w, (u16)(vh4.w >> 16)};
    #pragma unroll
    for (int jj = 0; jj < 8; ++jj) {
      int d = d0v + jj;
      int byte = (d * 224 + k) * 2; byte ^= (((d & 7) ^ ((d >> 3) & 7)) << 4);
      *(u16*)(Vh + byte) = eh[jj];
    }
  }
  for (int idx = t; idx < 64 * 27; idx += 512) {   // zero-pad cols 197..223
    int d = idx / 27, k = 197 + idx % 27;
    int byte = (d * 224 + k) * 2; byte ^= (((d & 7) ^ ((d >> 3) & 7)) << 4);
    *(u16*)(Vh + byte) = 0;
  }
  // ---- TvT: [64d][64t] bf16, t<30 = tvv[t][d], 32<=t<62 = tvh[t-32][d] ----
  for (int i = t; i < 4096; i += 512) {
    int d = i >> 6, tt = i & 63;
    float vv = 0.f;
    if (tt < 30) vv = tvv[tt * 64 + d];
    else if (tt >= 32 && tt < 62) vv = tvh[(tt - 32) * 64 + d];
    int byte = (d * 64 + tt) * 2; byte ^= (((d & 7) ^ ((d >> 3) & 7)) << 4);
    *(u16*)(TvT + byte) = bf16rn(vv);
  }

  // ---- Q fragments ----
  bool active = (q0 + 16 * w) < NN;
  bf16x8 qh[2], ql_[2];
  {
    int qg = q0 + 16 * w + fr; int qc = qg > 196 ? 196 : qg;
    const u16* qr  = qkvhi + qbase + (size_t)qc * C3 + h * DD;
    const u16* qr2 = qkvlo + qbase + (size_t)qc * C3 + h * DD;
    qh[0]  = *(const bf16x8*)(qr + 8 * fq);
    qh[1]  = *(const bf16x8*)(qr + 32 + 8 * fq);
    ql_[0] = *(const bf16x8*)(qr2 + 8 * fq);
    ql_[1] = *(const bf16x8*)(qr2 + 32 + 8 * fq);
  }
  __syncthreads();   // B1

  // ---- S passes 1+2 vs Khi ----
  f32x4 sacc[17] = {};
  if (active) {
    #pragma unroll
    for (int ks = 0; ks < 2; ++ks)
      #pragma unroll
      for (int nf = 0; nf < 17; ++nf) {
        int row = 16 * nf + fr;
        int byte = row * 128 + 64 * ks + 16 * fq; byte ^= (row & 7) << 4;
        bf16x8 kf = *(const bf16x8*)(Ak + byte);
        sacc[nf] = __builtin_amdgcn_mfma_f32_16x16x32_bf16(qh[ks],  kf, sacc[nf], 0, 0, 0);
        sacc[nf] = __builtin_amdgcn_mfma_f32_16x16x32_bf16(ql_[ks], kf, sacc[nf], 0, 0, 0);
      }
  }
  __syncthreads();   // B2

  // ---- K lo + tab lo (overlay) ----
  for (int i = w; i < 26; i += 8) {
    int kk = 8 * i + kr; if (kk > 196) kk = 196;
    size_t src = qbase + (size_t)kk * C3 + CC + h * DD + chunk;
    __builtin_amdgcn_global_load_lds(
        (const __attribute__((address_space(1))) void*)(qkvlo + src),
        (__attribute__((address_space(3))) void*)(Ak + i * 1024), 16, 0, 0);
  }
  {
    int tr = 8 * w + kr;
    __builtin_amdgcn_global_load_lds(
        (const __attribute__((address_space(1))) void*)(tabKlo + tr * 64 + chunk),
        (__attribute__((address_space(3))) void*)(Ak + 26624 + w * 1024), 16, 0, 0);
  }
  __syncthreads();   // B3

  // ---- S pass 3 (qh . Klo) ----
  if (active) {
    #pragma unroll
    for (int ks = 0; ks < 2; ++ks)
      #pragma unroll
      for (int nf = 0; nf < 17; ++nf) {
        int row = 16 * nf + fr;
        int byte = row * 128 + 64 * ks + 16 * fq; byte ^= (row & 7) << 4;
        bf16x8 kf = *(const bf16x8*)(Ak + byte);
        sacc[nf] = __builtin_amdgcn_mfma_f32_16x16x32_bf16(qh[ks], kf, sacc[nf], 0, 0, 0);
      }
  }
  __syncthreads();   // B3.5: all Ak reads complete -> region reusable (PvB)

  // ---- PvPh -> PvB [128][60]bf16 (stride 120B); gather; softmax; pack ----
  unsigned pk01[13], pk23[13];
  if (active) {
    #pragma unroll
    for (int nf = 13; nf < 17; ++nf)
      #pragma unroll
      for (int r = 0; r < 4; ++r) {
        int c = 16 * (nf - 13) + fr;
        if (c < 60) {
          int row = 16 * w + 4 * fq + r;
          *(u16*)(PvB + row * 120 + 2 * c) = bf16rn(sacc[nf][r]);
        }
      }
    float ex[13][4];
    float mrow[4] = {-1e30f, -1e30f, -1e30f, -1e30f};
    #pragma unroll
    for (int r = 0; r < 4; ++r) {
      int ql2 = 16 * w + 4 * fq + r; int qg = q0 + ql2;
      int qc = qg > 196 ? 196 : qg;
      int gq = (qc > 0) ? (qc - 1) / 14 : 0;
      int cq = (qc > 0) ? (qc - 1) % 14 : 0;
      #pragma unroll
      for (int nf = 0; nf < 13; ++nf) {
        int k = 16 * nf + fr;
        float s;
        if (k < 197) {
          int fv  = (qc == 0 || k == 0) ? 0 : ((k - 1) / 14 - gq + 15);
          int fh2 = (qc == 0 || k == 0) ? 0 : ((k - 1) % 14 - cq + 15);
          float pv = bf16tof(*(const u16*)(PvB + ql2 * 120 + 2 * fv));
          float ph = bf16tof(*(const u16*)(PvB + ql2 * 120 + 2 * (30 + fh2)));
          s = (sacc[nf][r] + pv + ph) * SCALE;
        } else s = -1e30f;
        ex[nf][r] = s;
        mrow[r] = fmaxf(mrow[r], s);
      }
    }
    #pragma unroll
    for (int r = 0; r < 4; ++r)
      #pragma unroll
      for (int mk = 1; mk < 16; mk <<= 1) mrow[r] = fmaxf(mrow[r], __shfl_xor(mrow[r], mk));
    float sum[4] = {0.f, 0.f, 0.f, 0.f};
    #pragma unroll
    for (int nf = 0; nf < 13; ++nf)
      #pragma unroll
      for (int r = 0; r < 4; ++r) {
        ex[nf][r] = __expf(ex[nf][r] - mrow[r]);
        sum[r] += ex[nf][r];
      }
    float inv[4];
    #pragma unroll
    for (int r = 0; r < 4; ++r) {
      #pragma unroll
      for (int mk = 1; mk < 16; mk <<= 1) sum[r] += __shfl_xor(sum[r], mk);
      inv[r] = 1.f / sum[r];
    }
    #pragma unroll
    for (int nf = 0; nf < 13; ++nf) {
      pk01[nf] = (unsigned)bf16rn(ex[nf][0] * inv[0]) |
                 ((unsigned)bf16rn(ex[nf][1] * inv[1]) << 16);
      pk23[nf] = (unsigned)bf16rn(ex[nf][2] * inv[2]) |
                 ((unsigned)bf16rn(ex[nf][3] * inv[3]) << 16);
    }
  } else {
    #pragma unroll
    for (int nf = 0; nf < 13; ++nf) { pk01[nf] = 0; pk23[nf] = 0; }
  }
  __syncthreads();   // B4: PvB reads done -> region reusable (Phi/W)

  int qf = w & 3, hs2 = w >> 2;
  int prow = 16 * qf + fr;                         // = W A-row too
  int pswz = ((prow & 7) ^ ((prow >> 3) & 7)) << 4;
  int vrow0 = 32 * hs2 + fr, vrow1 = vrow0 + 16;   // = TvT B-rows too
  int vswz0 = ((vrow0 & 7) ^ ((vrow0 >> 3) & 7)) << 4;
  int vswz1 = ((vrow1 & 7) ^ ((vrow1 >> 3) & 7)) << 4;

  for (int p = 0; p < 2; ++p) {
    if (p) __syncthreads();    // protect prior half's W/Phi reads before overwrite

    // P-write for q-half p by owner waves
    if ((w >> 2) == p) {
      int rbase = 16 * (w & 3);
      #pragma unroll
      for (int nf = 0; nf < 14; ++nf)
        #pragma unroll
        for (int r = 0; r < 4; ++r) {
          int k = 16 * nf + fr;
          int pr = rbase + 4 * fq + r;
          u16 val = 0;
          if (nf < 13) {
            unsigned pk = (r < 2) ? pk01[nf] : pk23[nf];
            val = (r & 1) ? (u16)(pk >> 16) : (u16)(pk & 0xFFFF);
          }
          int byte = (pr * 224 + k) * 2; byte ^= (((pr & 7) ^ ((pr >> 3) & 7)) << 4);
          *(u16*)(Phi + byte) = val;
        }
    }
    __syncthreads();   // B5: P ready

    // AV (hi-only): wave (qf, hs2) -> q rows 16qf.., d frags {2hs2, 2hs2+1}
    f32x4 ov0 = {}, ov1 = {};
    #pragma unroll
    for (int ks = 0; ks < 7; ++ks) {
      int co = 64 * ks + 16 * fq;
      bf16x8 pah = *(const bf16x8*)(Phi + ((prow * 448 + co) ^ pswz));
      bf16x8 v0  = *(const bf16x8*)(Vh + ((vrow0 * 448 + co) ^ vswz0));
      bf16x8 v1  = *(const bf16x8*)(Vh + ((vrow1 * 448 + co) ^ vswz1));
      ov0 = __builtin_amdgcn_mfma_f32_16x16x32_bf16(pah, v0, ov0, 0, 0, 0);
      ov1 = __builtin_amdgcn_mfma_f32_16x16x32_bf16(pah, v1, ov1, 0, 0, 0);
    }

    // bucket sums Bv/Bh via VALU over P in LDS -> BvBh bf16
    for (int s = t; s < 1920; s += 512) {
      int q = s / 30, rem = s % 30;
      int isH = rem >= 15 ? 1 : 0, a = rem - 15 * isH;
      int sw = ((q & 7) ^ ((q >> 3) & 7)) << 4;
      float acc = 0.f;
      if (a == 14) {
        acc = bf16tof(*(const u16*)(Phi + (((q * 224 + 0) * 2) ^ sw)));
      } else if (!isH) {
        int k0b = 1 + 14 * a;
        #pragma unroll
        for (int j = 0; j < 14; ++j)
          acc += bf16tof(*(const u16*)(Phi + (((q * 224 + k0b + j) * 2) ^ sw)));
      } else {
        #pragma unroll
        for (int i2 = 0; i2 < 14; ++i2)
          acc += bf16tof(*(const u16*)(Phi + (((q * 224 + 1 + a + 14 * i2) * 2) ^ sw)));
      }
      BvBh[q * 32 + 16 * isH + a] = bf16rn(acc);
    }
    __syncthreads();   // B6: BvBh ready, Phi dead

    // W build: W[q][t] bf16 = shifted bucket coefficients
    for (int i = t; i < 4096; i += 512) {
      int q = i >> 6, tt = i & 63;
      int half = tt >> 5, u = tt & 31;
      int qg = q0 + 64 * p + q;
      float val = 0.f;
      if (qg == 0) {
        if (u == 0) {
          #pragma unroll
          for (int a = 0; a < 15; ++a) val += bf16tof(BvBh[16 * half + a]);
        }
      } else if (qg < NN) {
        int m = qg - 1;
        int sel = half ? (m % 14) : (m / 14);
        if (u == 0) val = bf16tof(BvBh[q * 32 + 16 * half + 14]);
        else {
          int a = u - 15 + sel;
          if (a >= 0 && a < 14) val = bf16tof(BvBh[q * 32 + 16 * half + a]);
        }
      }
      int byte = (q * 64 + tt) * 2; byte ^= (((q & 7) ^ ((q >> 3) & 7)) << 4);
      *(u16*)(Wb + byte) = bf16rn(val);
    }
    __syncthreads();   // B7: W ready

    // rel-v MFMA: out_rel = W @ TvT  (K = 64, 2 steps)
    f32x4 rv0 = {}, rv1 = {};
    #pragma unroll
    for (int ks2 = 0; ks2 < 2; ++ks2) {
      int co = 64 * ks2 + 16 * fq;
      bf16x8 wa = *(const bf16x8*)(Wb + ((prow * 128 + co) ^ pswz));
      bf16x8 t0 = *(const bf16x8*)(TvT + ((vrow0 * 128 + co) ^ vswz0));
      bf16x8 t1 = *(const bf16x8*)(TvT + ((vrow1 * 128 + co) ^ vswz1));
      rv0 = __builtin_amdgcn_mfma_f32_16x16x32_bf16(wa, t0, rv0, 0, 0, 0);
      rv1 = __builtin_amdgcn_mfma_f32_16x16x32_bf16(wa, t1, rv1, 0, 0, 0);
    }

    // epilogue store
    #pragma unroll
    for (int r = 0; r < 4; ++r) {
      int qlocal = 16 * qf + 4 * fq + r;
      int qg = q0 + 64 * p + qlocal;
      if (qg >= NN) continue;
      float o0 = ov0[r] + rv0[r];
      float o1 = ov1[r] + rv1[r];
      int d0 = 32 * hs2 + fr, d1 = d0 + 16;
      size_t ob = (size_t)(b * NN + qg) * CC + h * DD;
      u16 hh, ll;
      split_bf16(o0, hh, ll); ohi[ob + d0] = hh; olo[ob + d0] = ll;
      split_bf16(o1, hh, ll); ohi[ob + d1] = hh; olo[ob + d1] = ll;
    }
  }
}

// ---------------------------------------------------------------------------
// Workspace (u16 units, 135.7 MB):
//   qkvhi 24,207,360 | qkvlo 24,207,360 | xhi/xlo 2x8,069,120 (reused ohi/olo)
//   weffhi/lo 2x1,228,800 | wphi/lo 2x409,600 | tabKhi/lo 2x4,096
// ---------------------------------------------------------------------------
extern "C" void kernel_launch(void* const* d_in, const int* in_sizes, int n_in,
                              void* d_out, int out_size, void* d_ws, size_t ws_size,
                              hipStream_t stream) {
  (void)in_sizes; (void)n_in; (void)out_size; (void)ws_size;
  const float* x     = (const float*)d_in[0];
  const float* w_qkv = (const float*)d_in[1];
  const float* b_qkv = (const float*)d_in[2];
  const float* la    = (const float*)d_in[3];
  const float* lb    = (const float*)d_in[4];
  const float* tkv   = (const float*)d_in[5];
  const float* tkh   = (const float*)d_in[6];
  const float* tvv   = (const float*)d_in[7];
  const float* tvh   = (const float*)d_in[8];
  const float* wp    = (const float*)d_in[9];
  const float* b_p   = (const float*)d_in[10];

  u16* qkvhi  = (u16*)d_ws;
  u16* qkvlo  = qkvhi + (size_t)24207360;
  u16* xhi    = qkvlo + (size_t)24207360;
  u16* xlo    = xhi + (size_t)8069120;
  u16* ohi    = xhi;                       // alias (x splits dead after gemm1)
  u16* olo    = xlo;
  u16* weffhi = xlo + (size_t)8069120;
  u16* wefflo = weffhi + (size_t)1228800;
  u16* wphi   = wefflo + (size_t)1228800;
  u16* wplo   = wphi + (size_t)409600;
  u16* tabKhi = wplo + (size_t)409600;
  u16* tabKlo = tabKhi + (size_t)4096;

  k_weff<<<(C3 * CC) / 256, 256, 0, stream>>>(w_qkv, la, lb, weffhi, wefflo);
  k_cvtw<<<(CC * CC) / 256, 256, 0, stream>>>(wp, wphi, wplo);
  k_prep<<<1, 256, 0, stream>>>(tkv, tkh, tabKhi, tabKlo);
  int n4x = (MTOT * CC) / 4;
  k_cvt<<<(n4x + 255) / 256, 256, 0, stream>>>(x, xhi, xlo, n4x);

  // qkv = x @ weff^T + b_qkv -> split bf16 output
  dim3 g1((MTOT + 127) / 128, C3 / 128);
  k_gemm_mfma<1><<<g1, dim3(256), 0, stream>>>(xhi, xlo, weffhi, wefflo, b_qkv,
                                               nullptr, qkvhi, qkvlo, MTOT, C3);

  // fused attention -> ohi/olo split
  k_attn<<<dim3(BB * HH, 2), 512, 0, stream>>>(qkvhi, qkvlo, tabKhi, tabKlo,
                                               tvv, tvh, ohi, olo);

  // out = o @ perm3(w_proj)^T + b_proj
  dim3 g2((MTOT + 127) / 128, CC / 128);
  k_gemm_mfma<0><<<g2, dim3(256), 0, stream>>>(ohi, olo, wphi, wplo, b_p,
                                               (float*)d_out, nullptr, nullptr, MTOT, CC);
}